// Round 2
// baseline (475.307 us; speedup 1.0000x reference)
//
#include <hip/hip_runtime.h>
#include <math.h>

#define NI 256
#define NJ 256
#define NK 1024
#define JCHUNK 32
#define HALO 16
#define LROW (HALO + NK + HALO)   // 1056 floats
#define FLT_MAX_ 3.402823466e+38f

typedef float float4v __attribute__((ext_vector_type(4)));

__device__ __forceinline__ float finalize(float n, float d) {
    float r = n / d;
    if (isnan(r)) r = 1.0f;
    else if (isinf(r)) r = (r > 0.f) ? FLT_MAX_ : -FLT_MAX_;
    return r;
}

__global__ __launch_bounds__(256, 8)
void semblance_kernel(const float* __restrict__ x, float* __restrict__ out) {
    // double-buffered rows of s1^2 and sum(x^2), 16-float zero halos each side
    __shared__ __align__(16) float s_num[2][LROW];
    __shared__ __align__(16) float s_den[2][LROW];

    const int tid  = threadIdx.x;
    const int i    = blockIdx.y;
    const int j0   = blockIdx.x * JCHUNK;
    const int base = tid * 4;          // this thread's first k

    // zero halos once; first in-loop barrier publishes them
    if (tid < HALO) {
        s_num[0][tid] = 0.f; s_den[0][tid] = 0.f;
        s_num[1][tid] = 0.f; s_den[1][tid] = 0.f;
        s_num[0][HALO + NK + tid] = 0.f; s_den[0][HALO + NK + tid] = 0.f;
        s_num[1][HALO + NK + tid] = 0.f; s_den[1][HALO + NK + tid] = 0.f;
    }

    const float* xi = x + (size_t)i * NJ * NK + base;

    // register ring: rows j-2..j+2 for j = j0 at loop entry
    float4v r0, r1, r2, r3, r4;
    r0 = (j0 - 2 >= 0) ? *(const float4v*)(xi + (size_t)(j0 - 2) * NK) : (float4v)0.f;
    r1 = (j0 - 1 >= 0) ? *(const float4v*)(xi + (size_t)(j0 - 1) * NK) : (float4v)0.f;
    r2 = *(const float4v*)(xi + (size_t)j0 * NK);
    r3 = (j0 + 1 < NJ) ? *(const float4v*)(xi + (size_t)(j0 + 1) * NK) : (float4v)0.f;
    r4 = (j0 + 2 < NJ) ? *(const float4v*)(xi + (size_t)(j0 + 2) * NK) : (float4v)0.f;

    for (int jj = 0; jj < JCHUNK; ++jj) {
        const int j = j0 + jj;
        const int b = jj & 1;

        // ---- j-window sums from the register ring ----
        float4v s = r0 + r1 + r2 + r3 + r4;
        float4v t = r0 * r0 + r1 * r1 + r2 * r2 + r3 * r3 + r4 * r4;
        *(float4v*)(&s_num[b][HALO + base]) = s * s;
        *(float4v*)(&s_den[b][HALO + base]) = t;

        // prefetch next row (j+3) now; latency hides under barrier + LDS phase
        float4v nxt = (float4v)0.f;
        if (jj + 1 < JCHUNK && j + 3 < NJ)
            nxt = *(const float4v*)(xi + (size_t)(j + 3) * NK);

        __syncthreads();

        // ---- k-window (20, pad (10,9)) from LDS: need [base-10, base+12] ----
        float fn[28], fd[28];
        const float4v* pn = (const float4v*)(&s_num[b][HALO + base - 12]);
        const float4v* pd = (const float4v*)(&s_den[b][HALO + base - 12]);
        #pragma unroll
        for (int q = 0; q < 7; ++q) {
            float4v a = pn[q];
            float4v c = pd[q];
            #pragma unroll
            for (int e = 0; e < 4; ++e) {
                fn[q * 4 + e] = a[e];
                fd[q * 4 + e] = c[e];
            }
        }

        // base window for e=0: idx [2, 21]
        float wn = 0.f, wd = 0.f;
        #pragma unroll
        for (int idx = 2; idx <= 21; ++idx) {
            wn += fn[idx];
            wd += fd[idx];
        }

        const int jlo = (j - 2 < 0) ? 0 : j - 2;
        const int jhi = (j + 2 > NJ - 1) ? NJ - 1 : j + 2;
        const float norm = (float)(jhi - jlo + 1);

        float4v o;
        o[0] = finalize(wn, wd * norm);
        #pragma unroll
        for (int e = 1; e < 4; ++e) {
            wn += fn[21 + e] - fn[1 + e];
            wd += fd[21 + e] - fd[1 + e];
            o[e] = finalize(wn, wd * norm);
        }

        *(float4v*)(out + ((size_t)i * NJ + j) * NK + base) = o;

        // slide the ring (static names — no scratch)
        r0 = r1; r1 = r2; r2 = r3; r3 = r4; r4 = nxt;
        // no second barrier: next iteration writes the OTHER buffer; the
        // barrier at jj+1 orders those writes after all reads of buffer b
    }
}

extern "C" void kernel_launch(void* const* d_in, const int* in_sizes, int n_in,
                              void* d_out, int out_size, void* d_ws, size_t ws_size,
                              hipStream_t stream) {
    const float* x = (const float*)d_in[0];
    float* out = (float*)d_out;
    dim3 grid(NJ / JCHUNK, NI);   // (8, 256) = 2048 blocks -> 8 blocks/CU
    semblance_kernel<<<grid, 256, 0, stream>>>(x, out);
}

// Round 3
// 145.936 us; speedup vs baseline: 3.2570x; 3.2570x over previous
//
#include <hip/hip_runtime.h>
#include <math.h>

#define NI 256
#define NJ 256
#define NK 1024
#define JCHUNK 32
#define HALO 16
#define LROW (HALO + NK + HALO)   // 1056 floats
#define FLT_MAX_ 3.402823466e+38f

typedef float float4v __attribute__((ext_vector_type(4)));
typedef float float2v __attribute__((ext_vector_type(2)));

__device__ __forceinline__ float finalize(float n, float d) {
    float r = n / d;
    if (isnan(r)) r = 1.0f;
    else if (isinf(r)) r = (r > 0.f) ? FLT_MAX_ : -FLT_MAX_;
    return r;
}

// Window sums over fn[idx], idx = k - (base-12):
//   w0 = fn[2..21]; w_{e+1} = w_e + fn[22+e] - fn[2+e]
// Reads: float2 @ [base-10] (fn2,fn3), 5x float4 @ [base-8..base+8] (fn4..fn23),
//        scalar @ [base+12] (fn24).
__device__ __forceinline__ void kwindow(const float* __restrict__ row, int base,
                                        float& w0, float& w1, float& w2, float& w3) {
    float2v f23 = *(const float2v*)(row + HALO + base - 10);
    const float4v* p = (const float4v*)(row + HALO + base - 8);
    float4v q1 = p[0], q2 = p[1], q3 = p[2], q4 = p[3], q5 = p[4];
    float f24 = row[HALO + base + 12];
    float mid = (q1[0] + q1[1] + q1[2] + q1[3]) + (q2[0] + q2[1] + q2[2] + q2[3])
              + (q3[0] + q3[1] + q3[2] + q3[3]) + (q4[0] + q4[1] + q4[2] + q4[3]);
    w0 = f23[0] + f23[1] + mid + q5[0] + q5[1];
    w1 = w0 + q5[2] - f23[0];
    w2 = w1 + q5[3] - f23[1];
    w3 = w2 + f24   - q1[0];
}

__global__ __launch_bounds__(256, 6)
void semblance_kernel(const float* __restrict__ x, float* __restrict__ out) {
    __shared__ __align__(16) float s_num[2][LROW];
    __shared__ __align__(16) float s_den[2][LROW];

    const int tid  = threadIdx.x;
    const int i    = blockIdx.y;
    const int j0   = blockIdx.x * JCHUNK;
    const int base = tid * 4;

    if (tid < HALO) {
        s_num[0][tid] = 0.f; s_den[0][tid] = 0.f;
        s_num[1][tid] = 0.f; s_den[1][tid] = 0.f;
        s_num[0][HALO + NK + tid] = 0.f; s_den[0][HALO + NK + tid] = 0.f;
        s_num[1][HALO + NK + tid] = 0.f; s_den[1][HALO + NK + tid] = 0.f;
    }

    const float* xi = x + (size_t)i * NJ * NK + base;

    // register ring: rows j-2..j+2 for j = j0
    float4v r0, r1, r2, r3, r4;
    r0 = (j0 - 2 >= 0) ? *(const float4v*)(xi + (size_t)(j0 - 2) * NK) : (float4v)0.f;
    r1 = (j0 - 1 >= 0) ? *(const float4v*)(xi + (size_t)(j0 - 1) * NK) : (float4v)0.f;
    r2 = *(const float4v*)(xi + (size_t)j0 * NK);
    r3 = (j0 + 1 < NJ) ? *(const float4v*)(xi + (size_t)(j0 + 1) * NK) : (float4v)0.f;
    r4 = (j0 + 2 < NJ) ? *(const float4v*)(xi + (size_t)(j0 + 2) * NK) : (float4v)0.f;

    for (int jj = 0; jj < JCHUNK; ++jj) {
        const int j = j0 + jj;
        const int b = jj & 1;

        float4v s = r0 + r1 + r2 + r3 + r4;
        float4v t = r0 * r0 + r1 * r1 + r2 * r2 + r3 * r3 + r4 * r4;
        *(float4v*)(&s_num[b][HALO + base]) = s * s;
        *(float4v*)(&s_den[b][HALO + base]) = t;

        // prefetch next ring row before the barrier; latency hides under k-phase
        float4v nxt = (float4v)0.f;
        if (jj + 1 < JCHUNK && j + 3 < NJ)
            nxt = *(const float4v*)(xi + (size_t)(j + 3) * NK);

        __syncthreads();

        float wn0, wn1, wn2, wn3, wd0, wd1, wd2, wd3;
        kwindow(s_num[b], base, wn0, wn1, wn2, wn3);
        kwindow(s_den[b], base, wd0, wd1, wd2, wd3);

        const int jlo = (j - 2 < 0) ? 0 : j - 2;
        const int jhi = (j + 2 > NJ - 1) ? NJ - 1 : j + 2;
        const float norm = (float)(jhi - jlo + 1);

        float4v o;
        o[0] = finalize(wn0, wd0 * norm);
        o[1] = finalize(wn1, wd1 * norm);
        o[2] = finalize(wn2, wd2 * norm);
        o[3] = finalize(wn3, wd3 * norm);
        *(float4v*)(out + ((size_t)i * NJ + j) * NK + base) = o;

        r0 = r1; r1 = r2; r2 = r3; r3 = r4; r4 = nxt;
        // single barrier per iteration: next iter writes the OTHER LDS buffer;
        // its barrier orders those writes after all reads of this buffer
    }
}

extern "C" void kernel_launch(void* const* d_in, const int* in_sizes, int n_in,
                              void* d_out, int out_size, void* d_ws, size_t ws_size,
                              hipStream_t stream) {
    const float* x = (const float*)d_in[0];
    float* out = (float*)d_out;
    dim3 grid(NJ / JCHUNK, NI);   // (8, 256) = 2048 blocks
    semblance_kernel<<<grid, 256, 0, stream>>>(x, out);
}

// Round 4
// 141.607 us; speedup vs baseline: 3.3565x; 1.0306x over previous
//
#include <hip/hip_runtime.h>
#include <math.h>

#define NI 256
#define NJ 256
#define NK 1024
#define JCHUNK 32
#define KSEG 256            // per-wave k segment
#define HALO 16             // LDS halo floats on each side of the segment
#define WREG 304            // floats per wave region (288 used, padded to 16B)
#define FLT_MAX_ 3.402823466e+38f

typedef float float4v __attribute__((ext_vector_type(4)));
typedef float float2v __attribute__((ext_vector_type(2)));

__device__ __forceinline__ float finalize(float n, float d) {
    // |rcp err| ~1 ulp, threshold is 1.56e-2 absolute -> plenty of headroom.
    // d==0: rcp -> inf; n>0 -> inf -> FLT_MAX; n==0 -> 0*inf = nan -> 1.0 (matches 0/0).
    float r = n * __builtin_amdgcn_rcpf(d);
    if (isnan(r)) r = 1.0f;
    else if (isinf(r)) r = (r > 0.f) ? FLT_MAX_ : -FLT_MAX_;
    return r;
}

// Sliding 20-window sums along k. Window for elem e: [base-10+e, base+9+e].
// Reads from the wave-local region: float2 @ HALO+base-10, 5x float4 @ HALO+base-8,
// scalar @ HALO+base+12.
__device__ __forceinline__ void kwindow(const float* __restrict__ row, int base,
                                        float& w0, float& w1, float& w2, float& w3) {
    float2v f23 = *(const float2v*)(row + HALO + base - 10);
    const float4v* p = (const float4v*)(row + HALO + base - 8);
    float4v q1 = p[0], q2 = p[1], q3 = p[2], q4 = p[3], q5 = p[4];
    float f24 = row[HALO + base + 12];
    float mid = (q1[0] + q1[1] + q1[2] + q1[3]) + (q2[0] + q2[1] + q2[2] + q2[3])
              + (q3[0] + q3[1] + q3[2] + q3[3]) + (q4[0] + q4[1] + q4[2] + q4[3]);
    w0 = f23[0] + f23[1] + mid + q5[0] + q5[1];
    w1 = w0 + q5[2] - f23[0];
    w2 = w1 + q5[3] - f23[1];
    w3 = w2 + f24   - q1[0];
}

__global__ __launch_bounds__(256, 4)
void semblance_kernel(const float* __restrict__ x, float* __restrict__ out) {
    // one private region per wave: [wave][num|den][WREG] — no cross-wave sharing
    __shared__ __align__(16) float lds[4][2][WREG];

    const int tid  = threadIdx.x;
    const int lane = tid & 63;
    const int wave = tid >> 6;
    const int i    = blockIdx.y;
    const int j0   = blockIdx.x * JCHUNK;
    const int k0   = wave * KSEG;
    const int base = lane * 4;                 // within-segment k offset

    float* Wn = &lds[wave][0][0];
    float* Wd = &lds[wave][1][0];

    const float* xi = x + (size_t)i * NJ * NK;
    const float* xk = xi + k0 + base;          // this lane's main k column

    // halo assignment: lanes 0-3 -> left halo slots, lanes 4-7 -> right halo slots
    const bool hal   = (lane < 8);
    const int  hslot = (lane < 4) ? (4 * lane) : (KSEG + 4 * lane);  // float slot
    const int  hk    = k0 - HALO + hslot;      // global k of halo slot (mult of 4)
    const bool hkok  = (hk >= 0) && (hk < NK);
    const float* xh  = xi + hk;

    // register ring: rows j-2..j+2 for j = j0
    float4v r0, r1, r2, r3, r4;
    r0 = (j0 - 2 >= 0) ? *(const float4v*)(xk + (size_t)(j0 - 2) * NK) : (float4v)0.f;
    r1 = (j0 - 1 >= 0) ? *(const float4v*)(xk + (size_t)(j0 - 1) * NK) : (float4v)0.f;
    r2 = *(const float4v*)(xk + (size_t)j0 * NK);
    r3 = (j0 + 1 < NJ) ? *(const float4v*)(xk + (size_t)(j0 + 1) * NK) : (float4v)0.f;
    r4 = (j0 + 2 < NJ) ? *(const float4v*)(xk + (size_t)(j0 + 2) * NK) : (float4v)0.f;

    for (int jj = 0; jj < JCHUNK; ++jj) {
        const int j = j0 + jj;

        // halo lanes reload their 5 rows (4/5 are L1-hot from previous iters)
        float4v h0 = (float4v)0.f, h1 = (float4v)0.f, h2 = (float4v)0.f,
                h3 = (float4v)0.f, h4 = (float4v)0.f;
        if (hal && hkok) {
            if (j - 2 >= 0) h0 = *(const float4v*)(xh + (size_t)(j - 2) * NK);
            if (j - 1 >= 0) h1 = *(const float4v*)(xh + (size_t)(j - 1) * NK);
            h2 = *(const float4v*)(xh + (size_t)j * NK);
            if (j + 1 < NJ) h3 = *(const float4v*)(xh + (size_t)(j + 1) * NK);
            if (j + 2 < NJ) h4 = *(const float4v*)(xh + (size_t)(j + 2) * NK);
        }

        // prefetch next ring row early; latency hides under LDS phase
        float4v nxt = (float4v)0.f;
        if (jj + 1 < JCHUNK && j + 3 < NJ)
            nxt = *(const float4v*)(xk + (size_t)(j + 3) * NK);

        // main j-window sums -> LDS
        float4v s = r0 + r1 + r2 + r3 + r4;
        float4v t = r0 * r0 + r1 * r1 + r2 * r2 + r3 * r3 + r4 * r4;
        *(float4v*)(&Wn[HALO + base]) = s * s;
        *(float4v*)(&Wd[HALO + base]) = t;

        // halo j-window sums -> LDS
        if (hal) {
            float4v hs = h0 + h1 + h2 + h3 + h4;
            float4v ht = h0 * h0 + h1 * h1 + h2 * h2 + h3 * h3 + h4 * h4;
            *(float4v*)(&Wn[hslot]) = hs * hs;
            *(float4v*)(&Wd[hslot]) = ht;
        }

        // wave-internal write->read ordering: DS pipe is in-order per wave;
        // just stop the compiler from reordering across this point.
        __builtin_amdgcn_wave_barrier();
        asm volatile("" ::: "memory");

        float wn0, wn1, wn2, wn3, wd0, wd1, wd2, wd3;
        kwindow(Wn, base, wn0, wn1, wn2, wn3);
        kwindow(Wd, base, wd0, wd1, wd2, wd3);

        const int jlo = (j - 2 < 0) ? 0 : j - 2;
        const int jhi = (j + 2 > NJ - 1) ? NJ - 1 : j + 2;
        const float norm = (float)(jhi - jlo + 1);

        float4v o;
        o[0] = finalize(wn0, wd0 * norm);
        o[1] = finalize(wn1, wd1 * norm);
        o[2] = finalize(wn2, wd2 * norm);
        o[3] = finalize(wn3, wd3 * norm);
        *(float4v*)(out + ((size_t)i * NJ + j) * NK + k0 + base) = o;

        // slide the ring (static names — stays in registers)
        r0 = r1; r1 = r2; r2 = r3; r3 = r4; r4 = nxt;

        // order this iter's LDS reads before next iter's writes
        __builtin_amdgcn_wave_barrier();
        asm volatile("" ::: "memory");
    }
}

extern "C" void kernel_launch(void* const* d_in, const int* in_sizes, int n_in,
                              void* d_out, int out_size, void* d_ws, size_t ws_size,
                              hipStream_t stream) {
    const float* x = (const float*)d_in[0];
    float* out = (float*)d_out;
    dim3 grid(NJ / JCHUNK, NI);   // (8, 256) = 2048 blocks, 4 waves each
    semblance_kernel<<<grid, 256, 0, stream>>>(x, out);
}